// Round 4
// baseline (87.820 us; speedup 1.0000x reference)
//
#include <hip/hip_runtime.h>

#define CCH 128
#define SP  4096          // 64*64 spatial positions per (b,c)
#define LSTR 66           // attnmax LDS row stride in float2
#define TBL_N (9 * SP)

__device__ __forceinline__ float sigmoidf_(float z) {
  return 1.0f / (1.0f + __expf(-z));
}

// One-time gather table: tbl[s*4096+wh] = float2-LDS offset (sw*66+sh) or 0xFFFF.
__global__ __launch_bounds__(256) void k_table(unsigned short* __restrict__ tbl) {
  int i = blockIdx.x * 256 + threadIdx.x;
  if (i >= TBL_N) return;
  int s  = i >> 12, wh = i & (SP - 1);
  int q  = (s << 12) + wh;       // flat index into torch's reinterpreted view
  int wi = q / 576;  int r  = q - wi * 576;
  int hi = r / 9;    int kk = r - hi * 9;
  int di = kk / 3,   dj = kk - di * 3;
  int sw = wi + di - 1, sh = hi + dj - 1;
  tbl[i] = (((unsigned)sw < 64u) & ((unsigned)sh < 64u))
               ? (unsigned short)(sw * LSTR + sh) : (unsigned short)0xFFFFu;
}

// y[b,o,n] = sum_c attn_w[o][c] * x[b,c,n], written into d_out.
// Block = 128o x 128n tile, 256 threads, thread = 8o x 8n (64 VGPR acc).
// Weights transposed once into LDS wt[c][o]; main loop: 2 ds_read_b128 (w,
// 4-address broadcast, bank-disjoint) + 2 float4 x loads + 64 FMA per c.
__global__ __launch_bounds__(256, 1) void k_conv(
    const float* __restrict__ x, const float* __restrict__ attn_w,
    float* __restrict__ y) {
  __shared__ float wt[CCH * CCH];   // [c][o], 64 KB

  // stage + transpose weights (one-time): read w[o][c] as float4, scatter to wt[c][o]
  for (int k = 0; k < 16; k++) {
    int flat = k * 256 + threadIdx.x;       // 0..4095 float4s
    int o = flat >> 5, c0 = (flat & 31) << 2;
    float4 v = ((const float4*)attn_w)[flat];
    wt[(c0 + 0) * CCH + o] = v.x;
    wt[(c0 + 1) * CCH + o] = v.y;
    wt[(c0 + 2) * CCH + o] = v.z;
    wt[(c0 + 3) * CCH + o] = v.w;
  }
  __syncthreads();

  int b  = blockIdx.x >> 5;
  int n0 = ((blockIdx.x & 31) << 7) + ((threadIdx.x & 15) << 3);
  int o0 = (threadIdx.x >> 4) << 3;         // 0..120 step 8

  const float* xb = x + ((size_t)b << 19) + n0;

  float acc[8][8];
#pragma unroll
  for (int i = 0; i < 8; i++)
#pragma unroll
    for (int j = 0; j < 8; j++) acc[i][j] = 0.0f;

#pragma unroll 2
  for (int c = 0; c < CCH; c++) {
    float4 x0 = *(const float4*)&xb[(size_t)c << 12];
    float4 x1 = *(const float4*)&xb[((size_t)c << 12) + 4];
    float4 w0 = *(const float4*)&wt[(c << 7) + o0];
    float4 w1 = *(const float4*)&wt[(c << 7) + o0 + 4];
    float xs[8]  = {x0.x, x0.y, x0.z, x0.w, x1.x, x1.y, x1.z, x1.w};
    float ws8[8] = {w0.x, w0.y, w0.z, w0.w, w1.x, w1.y, w1.z, w1.w};
#pragma unroll
    for (int i = 0; i < 8; i++)
#pragma unroll
      for (int j = 0; j < 8; j++)
        acc[i][j] = fmaf(ws8[i], xs[j], acc[i][j]);
  }

  float* yb = y + ((size_t)b << 19) + n0;
#pragma unroll
  for (int i = 0; i < 8; i++) {
    *(float4*)&yb[(size_t)(o0 + i) << 12] =
        make_float4(acc[i][0], acc[i][1], acc[i][2], acc[i][3]);
    *(float4*)&yb[((size_t)(o0 + i) << 12) + 4] =
        make_float4(acc[i][4], acc[i][5], acc[i][6], acc[i][7]);
  }
}

// out[b,c,wh] = max_s se[s]*xg * sigmoid(se[s]*yg + attn_b[c]).
// Block = one (b,c) plane; x,y interleaved as float2 in padded LDS;
// gather = one ds_read_b64 per tap; result overwrites the y-plane in d_out.
template <bool TBL>
__global__ __launch_bounds__(256) void k_attnmax(
    const float* __restrict__ x, float* __restrict__ yo,
    const float* __restrict__ se_param, const float* __restrict__ attn_b,
    const unsigned short* __restrict__ tbl) {
  __shared__ __align__(16) float2 lxy[64 * LSTR];
  __shared__ float se9[12];

  int bc = blockIdx.x;            // b*128 + c
  int c  = bc & (CCH - 1);
  const float* xp = x  + ((size_t)bc << 12);
  float*       yp = yo + ((size_t)bc << 12);

  if (threadIdx.x < 9) se9[threadIdx.x] = sigmoidf_(se_param[threadIdx.x]);

  for (int i = threadIdx.x; i < SP / 4; i += 256) {   // 1024 float4 per plane
    float4 vx = ((const float4*)xp)[i];
    float4 vy = ((const float4*)yp)[i];
    float2* dst = &lxy[(i >> 4) * LSTR + ((i & 15) << 2)];
    *(float4*)(dst)     = make_float4(vx.x, vy.x, vx.y, vy.y);  // 16B-aligned
    *(float4*)(dst + 2) = make_float4(vx.z, vy.z, vx.w, vy.w);
  }
  float ab = attn_b[c];
  __syncthreads();

  for (int k = 0; k < 16; k++) {
    int wh = (k << 8) | threadIdx.x;
    float m = -3.4e38f;
#pragma unroll
    for (int s = 0; s < 9; s++) {
      int off; bool valid;
      if (TBL) {
        unsigned short t = tbl[(s << 12) | wh];       // coalesced, L2-hot
        valid = (t != 0xFFFFu);
        off = valid ? (int)t : 0;
      } else {
        int q  = (s << 12) + wh;
        int wi = q / 576;  int r  = q - wi * 576;
        int hi = r / 9;    int kk = r - hi * 9;
        int di = kk / 3,   dj = kk - di * 3;
        int sw = wi + di - 1, sh = hi + dj - 1;
        valid = ((unsigned)sw < 64u) & ((unsigned)sh < 64u);
        off = valid ? sw * LSTR + sh : 0;
      }
      float se = se9[s];
      float2 xy = lxy[off];                           // one ds_read_b64
      float v  = se * xy.x * sigmoidf_(fmaf(se, xy.y, ab));
      v = valid ? v : 0.0f;      // OOB tap contributes weighted=0
      m = fmaxf(m, v);
    }
    yp[wh] = m;                  // overwrite y-plane (y already staged in LDS)
  }
}

extern "C" void kernel_launch(void* const* d_in, const int* in_sizes, int n_in,
                              void* d_out, int out_size, void* d_ws, size_t ws_size,
                              hipStream_t stream) {
  const float* x        = (const float*)d_in[0];
  const float* se_param = (const float*)d_in[1];
  const float* attn_w   = (const float*)d_in[2];
  const float* attn_b   = (const float*)d_in[3];
  float* out = (float*)d_out;

  int B = in_sizes[0] / (CCH * SP);
  unsigned short* tbl = (unsigned short*)d_ws;
  bool use_tbl = ws_size >= (size_t)TBL_N * sizeof(unsigned short);

  if (use_tbl)
    k_table<<<dim3((TBL_N + 255) / 256), dim3(256), 0, stream>>>(tbl);

  k_conv<<<dim3(B * 32), dim3(256), 0, stream>>>(x, attn_w, out);

  if (use_tbl)
    k_attnmax<true><<<dim3(B * CCH), dim3(256), 0, stream>>>(
        x, out, se_param, attn_b, tbl);
  else
    k_attnmax<false><<<dim3(B * CCH), dim3(256), 0, stream>>>(
        x, out, se_param, attn_b, nullptr);
}

// Round 5
// 61.960 us; speedup vs baseline: 1.4174x; 1.4174x over previous
//
#include <hip/hip_runtime.h>

#define CCH 128
#define SP  4096          // 64*64 spatial positions per (b,c)
#define LSTR 66           // attnmax LDS row stride in float2
#define LSTRW 68          // conv LDS weight row stride (floats), 16B-aligned rows
#define TBL_N (9 * SP)    // 36864 = 144 blocks * 256
#define WT_OFF 18432      // float offset of wT inside d_ws (73728 B of tbl / 4)

__device__ __forceinline__ float sigmoidf_(float z) {
  return 1.0f / (1.0f + __expf(-z));
}

// One-time prep: gather table (blocks 0..143) + weight transpose (blocks 144..207).
__global__ __launch_bounds__(256) void k_prep(
    const float* __restrict__ attn_w, unsigned short* __restrict__ tbl,
    float* __restrict__ wT) {
  int i = blockIdx.x * 256 + threadIdx.x;
  if (i < TBL_N) {
    int s  = i >> 12, wh = i & (SP - 1);
    int q  = (s << 12) + wh;     // flat index into torch's reinterpreted view
    int wi = q / 576;  int r  = q - wi * 576;
    int hi = r / 9;    int kk = r - hi * 9;
    int di = kk / 3,   dj = kk - di * 3;
    int sw = wi + di - 1, sh = hi + dj - 1;
    tbl[i] = (((unsigned)sw < 64u) & ((unsigned)sh < 64u))
                 ? (unsigned short)(sw * LSTR + sh) : (unsigned short)0xFFFFu;
  } else {
    int j = i - TBL_N;
    if (j < CCH * CCH) {
      int o = j >> 7, c = j & (CCH - 1);
      wT[c * CCH + o] = attn_w[j];   // coalesced read, scattered write (once)
    }
  }
}

// y[b,o,n] = sum_c attn_w[o][c] * x[b,c,n], written into d_out.
// Block = 64o x 64n, 256 threads, thread = 4o x 4n (16 acc).
// Grid 1024 -> 4 blocks/CU (LDS 34KB), 16 waves/CU.
// Per c: 1 broadcast ds_read_b128 (conflict-free) + 1 coalesced float4 x + 16 FMA.
template <bool PRET>
__global__ __launch_bounds__(256, 4) void k_conv(
    const float* __restrict__ x, const float* __restrict__ w,  // wT if PRET else attn_w
    float* __restrict__ y) {
  __shared__ float wtl[CCH * LSTRW];   // [c][o-slice(64)] padded

  int blk   = blockIdx.x;
  int ohalf = blk & 1;
  int nslab = (blk >> 1) & 63;
  int b     = blk >> 7;
  int oblk  = ohalf << 6;

  if (PRET) {
    // wT[c][oblk..oblk+63] -> wtl, vector float4, conflict-free
#pragma unroll
    for (int k = 0; k < 8; k++) {
      int f = (k << 8) + threadIdx.x;          // 0..2047 float4s
      int c = f >> 4, j = f & 15;
      float4 v = ((const float4*)w)[(c << 5) + (oblk >> 2) + j];
      *(float4*)&wtl[c * LSTRW + (j << 2)] = v;
    }
  } else {
    // fallback: transpose attn_w in-kernel (coalesced read, 8-way-conflict scalar
    // write, prologue-only)
#pragma unroll
    for (int k = 0; k < 32; k++) {
      int f  = (k << 8) + threadIdx.x;         // 0..8191
      int c  = f & (CCH - 1), oo = f >> 7;     // oo 0..63
      wtl[c * LSTRW + oo] = w[(oblk + oo) * CCH + c];
    }
  }
  __syncthreads();

  int n0 = (nslab << 6) + ((threadIdx.x & 15) << 2);
  int o0 = (threadIdx.x >> 4) << 2;            // 0..60 step 4
  const float* xb = x + ((size_t)b << 19) + n0;

  float acc[4][4];
#pragma unroll
  for (int i = 0; i < 4; i++)
#pragma unroll
    for (int j = 0; j < 4; j++) acc[i][j] = 0.0f;

#pragma unroll 4
  for (int c = 0; c < CCH; c++) {
    float4 xv = *(const float4*)&xb[(size_t)c << 12];
    float4 wv = *(const float4*)&wtl[c * LSTRW + o0];
    float xs[4] = {xv.x, xv.y, xv.z, xv.w};
    float ws[4] = {wv.x, wv.y, wv.z, wv.w};
#pragma unroll
    for (int i = 0; i < 4; i++)
#pragma unroll
      for (int j = 0; j < 4; j++)
        acc[i][j] = fmaf(ws[i], xs[j], acc[i][j]);
  }

  float* yb = y + ((size_t)b << 19) + ((size_t)oblk << 12) + n0;
#pragma unroll
  for (int i = 0; i < 4; i++)
    *(float4*)&yb[(size_t)(o0 + i) << 12] =
        make_float4(acc[i][0], acc[i][1], acc[i][2], acc[i][3]);
}

// out[b,c,wh] = max_s se[s]*xg * sigmoid(se[s]*yg + attn_b[c]).
// Block = one (b,c) plane; x,y interleaved as float2 in padded LDS;
// k-loop unrolled x2 for independent tbl/ds latency chains.
template <bool TBL>
__global__ __launch_bounds__(256) void k_attnmax(
    const float* __restrict__ x, float* __restrict__ yo,
    const float* __restrict__ se_param, const float* __restrict__ attn_b,
    const unsigned short* __restrict__ tbl) {
  __shared__ __align__(16) float2 lxy[64 * LSTR];
  __shared__ float se9[12];

  int bc = blockIdx.x;            // b*128 + c
  int c  = bc & (CCH - 1);
  const float* xp = x  + ((size_t)bc << 12);
  float*       yp = yo + ((size_t)bc << 12);

  if (threadIdx.x < 9) se9[threadIdx.x] = sigmoidf_(se_param[threadIdx.x]);

  for (int i = threadIdx.x; i < SP / 4; i += 256) {   // 1024 float4 per plane
    float4 vx = ((const float4*)xp)[i];
    float4 vy = ((const float4*)yp)[i];
    float2* dst = &lxy[(i >> 4) * LSTR + ((i & 15) << 2)];
    *(float4*)(dst)     = make_float4(vx.x, vy.x, vx.y, vy.y);
    *(float4*)(dst + 2) = make_float4(vx.z, vy.z, vx.w, vy.w);
  }
  float ab = attn_b[c];
  __syncthreads();

  for (int k = 0; k < 16; k += 2) {
    int wh0 = (k << 8) | threadIdx.x;
    int wh1 = wh0 + 256;
    float m0 = -3.4e38f, m1 = -3.4e38f;
#pragma unroll
    for (int s = 0; s < 9; s++) {
      int off0, off1; bool vv0, vv1;
      if (TBL) {
        unsigned short t0 = tbl[(s << 12) | wh0];
        unsigned short t1 = tbl[(s << 12) | wh1];
        vv0 = (t0 != 0xFFFFu); vv1 = (t1 != 0xFFFFu);
        off0 = vv0 ? (int)t0 : 0; off1 = vv1 ? (int)t1 : 0;
      } else {
        int q0  = (s << 12) + wh0;
        int wi0 = q0 / 576;  int r0 = q0 - wi0 * 576;
        int hi0 = r0 / 9;    int kk0 = r0 - hi0 * 9;
        int sw0 = wi0 + kk0 / 3 - 1, sh0 = hi0 + kk0 % 3 - 1;
        vv0 = ((unsigned)sw0 < 64u) & ((unsigned)sh0 < 64u);
        off0 = vv0 ? sw0 * LSTR + sh0 : 0;
        int q1  = (s << 12) + wh1;
        int wi1 = q1 / 576;  int r1 = q1 - wi1 * 576;
        int hi1 = r1 / 9;    int kk1 = r1 - hi1 * 9;
        int sw1 = wi1 + kk1 / 3 - 1, sh1 = hi1 + kk1 % 3 - 1;
        vv1 = ((unsigned)sw1 < 64u) & ((unsigned)sh1 < 64u);
        off1 = vv1 ? sw1 * LSTR + sh1 : 0;
      }
      float se = se9[s];
      float2 a0 = lxy[off0];
      float2 a1 = lxy[off1];
      float r0 = se * a0.x * sigmoidf_(fmaf(se, a0.y, ab));
      float r1 = se * a1.x * sigmoidf_(fmaf(se, a1.y, ab));
      m0 = fmaxf(m0, vv0 ? r0 : 0.0f);
      m1 = fmaxf(m1, vv1 ? r1 : 0.0f);
    }
    yp[wh0] = m0;
    yp[wh1] = m1;
  }
}

extern "C" void kernel_launch(void* const* d_in, const int* in_sizes, int n_in,
                              void* d_out, int out_size, void* d_ws, size_t ws_size,
                              hipStream_t stream) {
  const float* x        = (const float*)d_in[0];
  const float* se_param = (const float*)d_in[1];
  const float* attn_w   = (const float*)d_in[2];
  const float* attn_b   = (const float*)d_in[3];
  float* out = (float*)d_out;

  int B = in_sizes[0] / (CCH * SP);
  unsigned short* tbl = (unsigned short*)d_ws;
  float* wT = (float*)d_ws + WT_OFF;
  bool use_ws = ws_size >= (size_t)(WT_OFF * 4 + CCH * CCH * 4);

  if (use_ws) {
    k_prep<<<dim3(208), dim3(256), 0, stream>>>(attn_w, tbl, wT);
    k_conv<true><<<dim3(B << 7), dim3(256), 0, stream>>>(x, wT, out);
    k_attnmax<true><<<dim3(B * CCH), dim3(256), 0, stream>>>(
        x, out, se_param, attn_b, tbl);
  } else {
    k_conv<false><<<dim3(B << 7), dim3(256), 0, stream>>>(x, attn_w, out);
    k_attnmax<false><<<dim3(B * CCH), dim3(256), 0, stream>>>(
        x, out, se_param, attn_b, nullptr);
  }
}

// Round 6
// 58.917 us; speedup vs baseline: 1.4906x; 1.0516x over previous
//
#include <hip/hip_runtime.h>

#define CCH 128
#define SP  4096          // 64*64 spatial positions per (b,c)
#define BSTR 11           // G-band stride per sh (floats); odd -> bank spread
#define BROWS 10          // band rows rb in [0,10)
#define BSZ (64 * BSTR)   // 704 floats per band (704 % 32 == 0 -> s-invariant banks)
#define GTOT (9 * BSZ)    // 6336 floats = 25.3 KB
#define TBL_N (9 * SP)
#define WT_OFF 18432      // float offset of wT inside d_ws (73728 B of tbl / 4)
#define WSTR 20           // conv LDS weight stride (floats): 16B-aligned, bank-spread

__device__ __forceinline__ float sigmoidf_(float z) {
  return 1.0f / (1.0f + __expf(-z));
}

// One-time prep: gather table (band-local offsets) + weight transpose.
// tbl[s*4096+wh] = s*BSZ + sh*BSTR + (sw - wi_lo(s) + 1), or 0xFFFF if OOB.
__global__ __launch_bounds__(256) void k_prep(
    const float* __restrict__ attn_w, unsigned short* __restrict__ tbl,
    float* __restrict__ wT) {
  int i = blockIdx.x * 256 + threadIdx.x;
  if (i < TBL_N) {
    int s  = i >> 12;
    int q  = i;                  // flat index into torch's reinterpreted view
    int wi = q / 576;  int r  = q - wi * 576;
    int hi = r / 9;    int kk = r - hi * 9;
    int di = kk / 3,   dj = kk - di * 3;
    int sw = wi + di - 1, sh = hi + dj - 1;
    bool valid = ((unsigned)sw < 64u) & ((unsigned)sh < 64u);
    int wilo = (64 * s) / 9;     // first wi touched by tap s
    int off  = s * BSZ + sh * BSTR + (sw - wilo + 1);
    tbl[i] = valid ? (unsigned short)off : (unsigned short)0xFFFFu;
  } else {
    int j = i - TBL_N;
    if (j < CCH * CCH) {
      int o = j >> 7, c = j & (CCH - 1);
      wT[c * CCH + o] = attn_w[j];   // coalesced read, scattered write (once)
    }
  }
}

// y[b,o,n] = sum_c attn_w[o][c]*x[b,c,n] -> d_out.
// Grid (B*16 slabs, 8 o-tiles): o-tile slowest => same-slab blocks share an XCD L2.
// Block 256 thr = 4 waves; wave = 4 o's x 256 n's; thread = 4o x 4n.
// Per c: wave-uniform ds_read_b128 broadcast (conflict-free) + 1024B coalesced x.
template <bool PRET>
__global__ __launch_bounds__(256) void k_conv(
    const float* __restrict__ x, const float* __restrict__ w,  // wT if PRET else attn_w
    float* __restrict__ y) {
  __shared__ float wtl[CCH * WSTR];   // [c][o-tile 16], 10 KB

  int slab = blockIdx.x;        // b*16 + nslab
  int ot   = blockIdx.y;        // 0..7
  int b    = slab >> 4, nslab = slab & 15;

  if (PRET) {
#pragma unroll
    for (int k = 0; k < 2; k++) {
      int t = (k << 8) + threadIdx.x;           // 0..511 float4s
      int c = t >> 2, j = t & 3;
      float4 v = ((const float4*)w)[(c << 5) + (ot << 2) + j];
      *(float4*)&wtl[c * WSTR + (j << 2)] = v;
    }
  } else {
#pragma unroll
    for (int k = 0; k < 8; k++) {
      int t  = (k << 8) + threadIdx.x;          // 0..2047
      int c  = t & (CCH - 1), ol = t >> 7;      // ol 0..15
      wtl[c * WSTR + ol] = w[((ot << 4) + ol) * CCH + c];
    }
  }
  __syncthreads();

  int lane = threadIdx.x & 63;
  int wv4  = (threadIdx.x >> 6) << 2;           // wave's o offset in tile: 0,4,8,12
  int n0   = (nslab << 8) + (lane << 2);
  const float* xb = x + ((size_t)b << 19) + n0;

  float acc[4][4];
#pragma unroll
  for (int i = 0; i < 4; i++)
#pragma unroll
    for (int j = 0; j < 4; j++) acc[i][j] = 0.0f;

#pragma unroll 8
  for (int c = 0; c < CCH; c++) {
    float4 xv = *(const float4*)&xb[(size_t)c << 12];      // 1024B/wave coalesced
    float4 wv = *(const float4*)&wtl[c * WSTR + wv4];      // same-addr broadcast
    float xs[4] = {xv.x, xv.y, xv.z, xv.w};
    float ws[4] = {wv.x, wv.y, wv.z, wv.w};
#pragma unroll
    for (int i = 0; i < 4; i++)
#pragma unroll
      for (int j = 0; j < 4; j++)
        acc[i][j] = fmaf(ws[i], xs[j], acc[i][j]);
  }

  int o0 = (ot << 4) + wv4;
  float* yb = y + ((size_t)b << 19) + ((size_t)o0 << 12) + n0;
#pragma unroll
  for (int i = 0; i < 4; i++)
    *(float4*)&yb[(size_t)i << 12] =
        make_float4(acc[i][0], acc[i][1], acc[i][2], acc[i][3]);
}

// out[b,c,wh] = max_s G_s[src(s,wh)], G_s[p] = se[s]*x[p]*sigmoid(se[s]*y[p]+ab).
// Phase 1: precompute G bands (5760 sigmoids/plane, 1.4/output instead of 9).
// Phase 2: gather = 9 x {u16 tbl, ds_read_b32, cndmask, fmax}. OOB candidate = 0.
template <bool TBL>
__global__ __launch_bounds__(256) void k_attnmax(
    const float* __restrict__ x, float* __restrict__ yo,
    const float* __restrict__ se_param, const float* __restrict__ attn_b,
    const unsigned short* __restrict__ tbl) {
  __shared__ float g[GTOT];
  __shared__ float se9[16];

  int bc = blockIdx.x;            // b*128 + c
  int c  = bc & (CCH - 1);
  const float* xp = x  + ((size_t)bc << 12);
  float*       yp = yo + ((size_t)bc << 12);

  if (threadIdx.x < 9) se9[threadIdx.x] = sigmoidf_(se_param[threadIdx.x]);
  float ab = attn_b[c];
  __syncthreads();

  // Phase 1: G bands. f -> (s, rb, sh); global row rg == sw by construction.
  for (int f = threadIdx.x; f < 9 * 64 * BROWS; f += 256) {
    int s   = f / (64 * BROWS);
    int rem = f - s * (64 * BROWS);
    int rb  = rem >> 6, sh = rem & 63;
    int rg  = (64 * s) / 9 - 1 + rb;
    float val = 0.0f;
    if ((unsigned)rg < 64u) {
      float se = se9[s];
      float xx = xp[(rg << 6) + sh];            // 256B coalesced row reads
      float yy = yp[(rg << 6) + sh];
      float t  = __expf(-fmaf(se, yy, ab));
      val = se * xx * __builtin_amdgcn_rcpf(1.0f + t);
    }
    g[s * BSZ + sh * BSTR + rb] = val;          // stride-11 scatter: 2-way max
  }
  __syncthreads();

  // Phase 2: gather + max; then overwrite the y-plane with the result.
  for (int k = 0; k < 16; k++) {
    int wh = (k << 8) | threadIdx.x;
    float m = -3.4e38f;
#pragma unroll
    for (int s = 0; s < 9; s++) {
      int off; bool vv;
      if (TBL) {
        unsigned short t = tbl[(s << 12) | wh];   // coalesced, L2-hot
        vv  = (t != 0xFFFFu);
        off = vv ? (int)t : 0;
      } else {
        int q  = (s << 12) + wh;
        int wi = q / 576;  int r  = q - wi * 576;
        int hi = r / 9;    int kk = r - hi * 9;
        int sw = wi + kk / 3 - 1, sh = hi + kk % 3 - 1;
        vv  = ((unsigned)sw < 64u) & ((unsigned)sh < 64u);
        int wilo = (64 * s) / 9;
        off = vv ? s * BSZ + sh * BSTR + (sw - wilo + 1) : 0;
      }
      float gv = g[off];                          // ds_read_b32, ~1-2 way banks
      m = fmaxf(m, vv ? gv : 0.0f);
    }
    yp[wh] = m;
  }
}

extern "C" void kernel_launch(void* const* d_in, const int* in_sizes, int n_in,
                              void* d_out, int out_size, void* d_ws, size_t ws_size,
                              hipStream_t stream) {
  const float* x        = (const float*)d_in[0];
  const float* se_param = (const float*)d_in[1];
  const float* attn_w   = (const float*)d_in[2];
  const float* attn_b   = (const float*)d_in[3];
  float* out = (float*)d_out;

  int B = in_sizes[0] / (CCH * SP);
  unsigned short* tbl = (unsigned short*)d_ws;
  float* wT = (float*)d_ws + WT_OFF;
  bool use_ws = ws_size >= (size_t)(WT_OFF * 4 + CCH * CCH * 4);

  if (use_ws) {
    k_prep<<<dim3(208), dim3(256), 0, stream>>>(attn_w, tbl, wT);
    k_conv<true><<<dim3(B * 16, 8), dim3(256), 0, stream>>>(x, wT, out);
    k_attnmax<true><<<dim3(B * CCH), dim3(256), 0, stream>>>(
        x, out, se_param, attn_b, tbl);
  } else {
    k_conv<false><<<dim3(B * 16, 8), dim3(256), 0, stream>>>(x, attn_w, out);
    k_attnmax<false><<<dim3(B * CCH), dim3(256), 0, stream>>>(
        x, out, se_param, attn_b, nullptr);
  }
}